// Round 17
// baseline (169.241 us; speedup 1.0000x reference)
//
#include <hip/hip_runtime.h>

// Inputs: float32. Output: float32. Compute: bf16 MFMA, f32 accumulate.
typedef __bf16 bf16;
typedef __bf16 bf16x4 __attribute__((ext_vector_type(4)));
typedef __bf16 bf16x8 __attribute__((ext_vector_type(8)));
typedef float  f32x4  __attribute__((ext_vector_type(4)));
typedef short  short4v __attribute__((ext_vector_type(4)));

#define GLOAD_LDS16(g, l) __builtin_amdgcn_global_load_lds( \
    (const __attribute__((address_space(1))) void*)(g),     \
    (__attribute__((address_space(3))) void*)(l), 16, 0, 0)

// v_exp_f32 (2^x) — avoid __exp2f (collides with glibc reserved identifier)
__device__ __forceinline__ float exp2_hw(float x) { return __builtin_amdgcn_exp2f(x); }

// 16x16x16 bf16 MFMA (A/B = 4 bf16 = 2 VGPR, C/D = 4 f32) — name varies by ROCm
#if __has_builtin(__builtin_amdgcn_mfma_f32_16x16x16bf16_1k)
__device__ __forceinline__ f32x4 mfma16(bf16x4 a, bf16x4 b, f32x4 c) {
    return __builtin_amdgcn_mfma_f32_16x16x16bf16_1k(
        __builtin_bit_cast(short4v, a), __builtin_bit_cast(short4v, b), c, 0, 0, 0);
}
#elif __has_builtin(__builtin_amdgcn_mfma_f32_16x16x16_bf16)
__device__ __forceinline__ f32x4 mfma16(bf16x4 a, bf16x4 b, f32x4 c) {
    return __builtin_amdgcn_mfma_f32_16x16x16_bf16(a, b, c, 0, 0, 0);
}
#else
__device__ __forceinline__ f32x4 mfma16(bf16x4 a, bf16x4 b, f32x4 c) {
    asm volatile("v_mfma_f32_16x16x16_bf16 %0, %1, %2, %0"
                 : "+v"(c) : "v"(a), "v"(b));
    return c;
}
#endif

// ---------------------------------------------------------------------------
// all five f32 inputs -> bf16 in ONE launch (segmented grid-stride, float4)
// ---------------------------------------------------------------------------
__global__ __launch_bounds__(256) void conv_all(
    const float* __restrict__ q_f, const float* __restrict__ wi_f,
    const float* __restrict__ bi_f, const float* __restrict__ wo_f,
    const float* __restrict__ bo_f,
    bf16* __restrict__ q_o, bf16* __restrict__ wi_o, bf16* __restrict__ bi_o,
    bf16* __restrict__ wo_o, bf16* __restrict__ bo_o)
{
    constexpr int N0 = 2097152;            // query /4
    constexpr int N1 = N0 + 786432;        // + w_in /4
    constexpr int N2 = N1 + 768;           // + b_in /4
    constexpr int N3 = N2 + 262144;        // + w_out /4
    constexpr int N4 = N3 + 256;           // + b_out /4
    int i = blockIdx.x * blockDim.x + threadIdx.x;
    const int stride = gridDim.x * blockDim.x;
    for (; i < N4; i += stride) {
        const float* src; bf16* dst; int off;
        if (i < N0)      { src = q_f;  dst = q_o;  off = i; }
        else if (i < N1) { src = wi_f; dst = wi_o; off = i - N0; }
        else if (i < N2) { src = bi_f; dst = bi_o; off = i - N1; }
        else if (i < N3) { src = wo_f; dst = wo_o; off = i - N2; }
        else             { src = bo_f; dst = bo_o; off = i - N3; }
        const float4 v = *(const float4*)(src + (size_t)off * 4);
        bf16x4 o = { (bf16)v.x, (bf16)v.y, (bf16)v.z, (bf16)v.w };
        *(bf16x4*)(dst + (size_t)off * 4) = o;
    }
}

// ---------------------------------------------------------------------------
// Shared 128x128/BK=64 NT main loop, T2-swizzled LDS.
// SWAP=false: acc[m][n], D row = A(M)-dim (s = fq*4+j), col = B(N)-dim (fr).
// SWAP=true:  acc[n][m] = mfma(b,a) -> D row = B(N)-dim (fq*4+j), col = A fr.
// Each KERNEL instantiates exactly one variant (round-16 lesson: dual
// instantiation in one kernel inflated VGPR 84->88, occupancy 26->19%).
// ---------------------------------------------------------------------------
template <bool SWAP>
__device__ __forceinline__ void gemm_mainloop_128(
    const bf16* __restrict__ A, const bf16* __restrict__ B, int K,
    int bm, int bn, bf16* As, bf16* Bs, f32x4 (&acc)[4][4])
{
    const int tid  = threadIdx.x;
    const int lane = tid & 63, fr = lane & 15, fq = lane >> 4;
    const int wave = tid >> 6;
    const int wr   = (wave >> 1) * 64, wc = (wave & 1) * 64;
    const int srow = tid >> 3, sj = tid & 7;
    const int sjs  = (sj ^ (srow & 7)) * 8;
    const int xo0  = (fq ^ (fr & 7)) * 8;
    const int xo1  = ((4 + fq) ^ (fr & 7)) * 8;

    const bf16* Ag = A + (size_t)(bm * 128 + srow) * K + sjs;
    const bf16* Bg = B + (size_t)(bn * 128 + srow) * K + sjs;
    bf16* Asw = As + srow * 64 + sj * 8;
    bf16* Bsw = Bs + srow * 64 + sj * 8;

    for (int k0 = 0; k0 < K; k0 += 64) {
        __syncthreads();
#pragma unroll
        for (int it = 0; it < 4; ++it)
            GLOAD_LDS16(Ag + k0 + (size_t)it * 32 * K, Asw + it * 32 * 64);
#pragma unroll
        for (int it = 0; it < 4; ++it)
            GLOAD_LDS16(Bg + k0 + (size_t)it * 32 * K, Bsw + it * 32 * 64);
        asm volatile("s_waitcnt vmcnt(0)" ::: "memory");
        __syncthreads();

#pragma unroll
        for (int ks = 0; ks < 2; ++ks) {
            const int xo = ks ? xo1 : xo0;
            bf16x8 a[4], b[4];
#pragma unroll
            for (int m = 0; m < 4; ++m)
                a[m] = *(const bf16x8*)&As[(wr + m * 16 + fr) * 64 + xo];
#pragma unroll
            for (int n = 0; n < 4; ++n)
                b[n] = *(const bf16x8*)&Bs[(wc + n * 16 + fr) * 64 + xo];
#pragma unroll
            for (int m = 0; m < 4; ++m)
#pragma unroll
                for (int n = 0; n < 4; ++n) {
                    if constexpr (SWAP)
                        acc[n][m] = __builtin_amdgcn_mfma_f32_16x16x32_bf16(b[n], a[m], acc[n][m], 0, 0, 0);
                    else
                        acc[m][n] = __builtin_amdgcn_mfma_f32_16x16x32_bf16(a[m], b[n], acc[m][n], 0, 0, 0);
                }
        }
    }
}

// ---------------------------------------------------------------------------
// Q/K projection (cols 0..2047) -> head-major q[bh][s][64] (PRE-SCALED by
// 0.125*log2e), k[bh][s][64]. Round-15 verbatim epilogue (normal orientation).
// grid = (M/128) * 16.
// ---------------------------------------------------------------------------
__global__ __launch_bounds__(256) void gemm_qk(
    const bf16* __restrict__ A, const bf16* __restrict__ B,
    const bf16* __restrict__ bias,
    bf16* __restrict__ qb_, bf16* __restrict__ kb_)
{
    constexpr int K = 1024, NTN = 16;
    constexpr float QSCALE = 0.18033688011112042f;  // 0.125 * log2(e)
    __shared__ bf16 As[128 * 64];
    __shared__ bf16 Bs[128 * 64];
    const int bm = blockIdx.x / NTN, bn = blockIdx.x % NTN;

    f32x4 acc[4][4] = {};
    gemm_mainloop_128<false>(A, B, K, bm, bn, As, Bs, acc);

    const int tid = threadIdx.x, lane = tid & 63;
    const int fr = lane & 15, fq = lane >> 4;
    const int wave = tid >> 6;
    const int wr = (wave >> 1) * 64, wc = (wave & 1) * 64;

    const int colbase = bn * 128 + wc;
    const int part = colbase >> 10;          // 0=Q 1=K (block-uniform)
    bf16* dst = (part == 0) ? qb_ : kb_;
    const bool isq = (part == 0);

#pragma unroll
    for (int n = 0; n < 4; ++n) {
        const int col = colbase + n * 16 + fr;
        const float bv = (float)bias[col];
        const int cl = col & 1023, h = cl >> 6, d = cl & 63;
#pragma unroll
        for (int m = 0; m < 4; ++m) {
            const int row0 = bm * 128 + wr + m * 16 + fq * 4;
            const int bb = row0 >> 11, s0 = row0 & 2047;
            const int bh = bb * 16 + h;
            if (isq) {
#pragma unroll
                for (int j = 0; j < 4; ++j)
                    dst[((size_t)bh * 2048 + s0 + j) * 64 + d] = (bf16)((acc[m][n][j] + bv) * QSCALE);
            } else {
#pragma unroll
                for (int j = 0; j < 4; ++j)
                    dst[((size_t)bh * 2048 + s0 + j) * 64 + d] = (bf16)(acc[m][n][j] + bv);
            }
        }
    }
}

// ---------------------------------------------------------------------------
// V projection (cols 2048..3071) -> vT[bh][64][s], SWAPPED mainloop (sole
// instantiation in this kernel): D row = weight-col (d), D col = s = fr ->
// 16 lanes write CONTIGUOUS s (32B chunks per d-row) instead of round-15's
// 8B chunks scattered over 4KB-apart rows. grid = (M/128) * 8.
// ---------------------------------------------------------------------------
__global__ __launch_bounds__(256) void gemm_v(
    const bf16* __restrict__ A, const bf16* __restrict__ Bv,
    const bf16* __restrict__ bias, bf16* __restrict__ vt_)
{
    constexpr int K = 1024, NTN = 8;
    __shared__ bf16 As[128 * 64];
    __shared__ bf16 Bs[128 * 64];
    const int bm = blockIdx.x / NTN, bn = blockIdx.x % NTN;

    f32x4 acc2[4][4] = {};
    // Bv = w_in + 2048*K (V rows); bn indexes within the V panel
    gemm_mainloop_128<true>(A, Bv, K, bm, bn, As, Bs, acc2);

    const int tid = threadIdx.x, lane = tid & 63;
    const int fr = lane & 15, fq = lane >> 4;
    const int wave = tid >> 6;
    const int wr = (wave >> 1) * 64, wc = (wave & 1) * 64;

    // head/addr constants (block/half uniform): panel col = bn*128+wc+n*16+fq*4+j
    const int h  = ((bn * 128 + wc) >> 6) & 15;      // head within batch
    const int bb = bm >> 4;                           // batch from row block
    const int sl = (bm & 15) * 128 + wr + fr;         // s_local base (+m*16)
    const int bh = bb * 16 + h;

#pragma unroll
    for (int n = 0; n < 4; ++n) {
        const int d0 = n * 16 + fq * 4;               // consecutive d over j
        const bf16x4 bvv = *(const bf16x4*)&bias[2048 + bn * 128 + wc + d0];
#pragma unroll
        for (int m = 0; m < 4; ++m) {
            const int s = sl + m * 16;                // per-lane s (fr inside)
#pragma unroll
            for (int j = 0; j < 4; ++j)
                vt_[((size_t)(bh * 64 + d0 + j)) * 2048 + s] =
                    (bf16)(acc2[n][m][j] + (float)bvv[j]);
        }
    }
}

// ---------------------------------------------------------------------------
__global__ __launch_bounds__(256) void gemm_out(
    const bf16* __restrict__ A, const bf16* __restrict__ B,
    const bf16* __restrict__ bias, float* __restrict__ C)
{
    constexpr int K = 1024, N = 1024, NTN = 8;
    __shared__ bf16 As[128 * 64];
    __shared__ bf16 Bs[128 * 64];
    const int bm = blockIdx.x / NTN, bn = blockIdx.x % NTN;

    f32x4 acc[4][4] = {};
    gemm_mainloop_128<false>(A, B, K, bm, bn, As, Bs, acc);

    const int tid = threadIdx.x, lane = tid & 63;
    const int fr = lane & 15, fq = lane >> 4;
    const int wave = tid >> 6;
    const int wr = (wave >> 1) * 64, wc = (wave & 1) * 64;

#pragma unroll
    for (int n = 0; n < 4; ++n) {
        const int col = bn * 128 + wc + n * 16 + fr;
        const float bv = (float)bias[col];
#pragma unroll
        for (int m = 0; m < 4; ++m) {
            const int row0 = bm * 128 + wr + m * 16 + fq * 4;
#pragma unroll
            for (int j = 0; j < 4; ++j)
                C[(size_t)(row0 + j) * N + col] = acc[m][n][j] + bv;
        }
    }
}

// ---------------------------------------------------------------------------
// Causal flash attention v10 (unchanged): causal pairing, 8 waves x 16 q,
// swapped QK^T, register-direct PV, ones-column denominator, nmax guard,
// no max tracking, 128-key barrier rounds (2x64 sub-tiles).
// ---------------------------------------------------------------------------
__global__ __launch_bounds__(512, 4) void attn10(
    const bf16* __restrict__ qb_, const bf16* __restrict__ kb_,
    const bf16* __restrict__ vt_, bf16* __restrict__ ctx)
{
    constexpr int S = 2048, EO = 1024;
    constexpr float NEG = -3.0e38f;
    __shared__ bf16 Ks[2][2][64 * 64];   // [dbuf][64-key sub-tile]
    __shared__ bf16 Vs[2][2][64 * 64];

    // bijective remap: 8 heads per XCD (64 blocks/XCD)
    const int idx = blockIdx.x;                 // 0..511
    const int orig = (idx & 7) * 64 + (idx >> 3);
    const int bh = orig >> 3;                   // 0..63
    const int p  = orig & 7;                    // pair index 0..7
    const int bb = bh >> 4, h = bh & 15;

    const int tid = threadIdx.x, lane = tid & 63, wave = tid >> 6;  // wave 0..7
    const int fr = lane & 15, fq = lane >> 4;

    const bf16* kh = kb_ + (size_t)bh * S * 64;
    const bf16* vh = vt_ + (size_t)bh * 64 * S;
    const bf16* qh = qb_ + (size_t)bh * S * 64;

    const int xo0 = (fq ^ (fr & 7)) * 8;
    const int xo1 = ((4 + fq) ^ (fr & 7)) * 8;

    // hoisted per-thread constants for QK/PV LDS addressing
    int krb[4], vslot[4], vrow[4];
#pragma unroll
    for (int n = 0; n < 4; ++n) {
        krb[n]   = (n * 16 + fr) * 64;
        vslot[n] = ((n * 2 + (fq >> 1)) ^ (fr & 7)) * 8 + (fq & 1) * 4;
        vrow[n]  = (n * 16 + fr) * 64;
    }

    // staging: 512 threads x 16B per sub-tile per operand (4 loads/round)
    const int r0 = tid >> 3, j0 = tid & 7;      // r0 0..63
    const int js = (j0 ^ (r0 & 7)) * 8;

#define STAGE128(buf, kt2)                                                    \
    do {                                                                      \
        GLOAD_LDS16(kh + (size_t)(((kt2) * 2) * 64 + r0) * 64 + js,           \
                    &Ks[buf][0][(r0 * 8 + j0) * 8]);                          \
        GLOAD_LDS16(kh + (size_t)(((kt2) * 2 + 1) * 64 + r0) * 64 + js,       \
                    &Ks[buf][1][(r0 * 8 + j0) * 8]);                          \
        GLOAD_LDS16(vh + (size_t)r0 * S + ((kt2) * 2) * 64 + js,              \
                    &Vs[buf][0][(r0 * 8 + j0) * 8]);                          \
        GLOAD_LDS16(vh + (size_t)r0 * S + ((kt2) * 2 + 1) * 64 + js,          \
                    &Vs[buf][1][(r0 * 8 + j0) * 8]);                          \
    } while (0)

    const bf16 one = (bf16)1.0f;
    const bf16x4 ones = { one, one, one, one };

#pragma unroll
    for (int sub = 0; sub < 2; ++sub) {
        const int qb = sub ? p : (15 - p);      // heavy q-block first
        const int q0 = qb * 128 + wave * 16;    // wave's first q row

        // Q fragments: B-operand of swapped QK^T; lane holds q = q0 + fr
        bf16x8 qf0, qf1;
        {
            const bf16* qr = qh + (size_t)(q0 + fr) * 64;
            qf0 = *(const bf16x8*)(qr + fq * 8);
            qf1 = *(const bf16x8*)(qr + 32 + fq * 8);
        }

        f32x4 acc[4] = {};   // O: acc[n2][j] -> d = n2*16+fr, q = q0 + fq*4+j
        f32x4 acc1 = {};     // softmax denominator, same row layout

        // protect LDS from previous sub's readers, then stage round 0
        __syncthreads();
        STAGE128(0, 0);
        asm volatile("s_waitcnt vmcnt(0)" ::: "memory");
        __syncthreads();

        int cur = 0;
        for (int kt2 = 0; kt2 <= qb; ++kt2) {   // 128-key rounds
            if (kt2 < qb) STAGE128(cur ^ 1, kt2 + 1);

#pragma unroll
            for (int half = 0; half < 2; ++half) {
                const int kt = 2 * kt2 + half;  // 64-key tile index
                // highest n-block with any unmasked key (<0: wave done)
                const int nmax = (q0 + 15 - kt * 64) >> 4;
                if (nmax < 0) continue;

                // S^T[key][q] = K . Q^T  (A = K frag, B = Q frag)
                f32x4 s[4];
                __builtin_amdgcn_s_setprio(1);
#pragma unroll
                for (int n = 0; n < 4; ++n) {
                    if (n > nmax) continue;
                    s[n] = f32x4{};
                    bf16x8 k0v = *(const bf16x8*)&Ks[cur][half][krb[n] + xo0];
                    bf16x8 k1v = *(const bf16x8*)&Ks[cur][half][krb[n] + xo1];
                    s[n] = __builtin_amdgcn_mfma_f32_16x16x32_bf16(k0v, qf0, s[n], 0, 0, 0);
                    s[n] = __builtin_amdgcn_mfma_f32_16x16x32_bf16(k1v, qf1, s[n], 0, 0, 0);
                }
                __builtin_amdgcn_s_setprio(0);

                // causal mask only on the wave's boundary tile (nmax <= 3)
                if (nmax <= 3) {
                    const int qrel = q0 - kt * 64 + fr;
#pragma unroll
                    for (int n = 0; n < 4; ++n) {
                        if (n > nmax) continue;
#pragma unroll
                        for (int j = 0; j < 4; ++j)
                            if (n * 16 + fq * 4 + j > qrel) s[n][j] = NEG;
                    }
                }

                // P = exp2(s); denominator via ones-column MFMA
                bf16x4 pb[4];
#pragma unroll
                for (int n = 0; n < 4; ++n) {
                    if (n > nmax) continue;
                    pb[n][0] = (bf16)exp2_hw(s[n][0]);
                    pb[n][1] = (bf16)exp2_hw(s[n][1]);
                    pb[n][2] = (bf16)exp2_hw(s[n][2]);
                    pb[n][3] = (bf16)exp2_hw(s[n][3]);
                    acc1 = mfma16(pb[n], ones, acc1);
                }

                // PV: O[q][d] += P.V via mfma 16x16x16 (A = pb from registers)
                __builtin_amdgcn_s_setprio(1);
#pragma unroll
                for (int n = 0; n < 4; ++n) {          // key block
                    if (n > nmax) continue;
#pragma unroll
                    for (int n2 = 0; n2 < 4; ++n2) {   // d block
                        bf16x4 vf = *(const bf16x4*)&Vs[cur][half][vrow[n2] + vslot[n]];
                        acc[n2] = mfma16(pb[n], vf, acc[n2]);
                    }
                }
                __builtin_amdgcn_s_setprio(0);
            }

            asm volatile("s_waitcnt vmcnt(0)" ::: "memory");
            __syncthreads();
            cur ^= 1;
        }

        // normalize: acc1[j] is the full denominator for q = q0 + fq*4 + j
        float linv[4];
#pragma unroll
        for (int j = 0; j < 4; ++j) linv[j] = __builtin_amdgcn_rcpf(acc1[j]);

#pragma unroll
        for (int n2 = 0; n2 < 4; ++n2)
#pragma unroll
            for (int j = 0; j < 4; ++j) {
                int qr_ = q0 + fq * 4 + j;
                ctx[((size_t)bb * S + qr_) * EO + h * 64 + n2 * 16 + fr] =
                    (bf16)(acc[n2][j] * linv[j]);
            }
    }
#undef STAGE128
}

// ---------------------------------------------------------------------------
extern "C" void kernel_launch(void* const* d_in, const int* in_sizes, int n_in,
                              void* d_out, int out_size, void* d_ws, size_t ws_size,
                              hipStream_t stream)
{
    constexpr int B = 4, S = 2048, E = 1024;
    constexpr int M = B * S;
    constexpr size_t N_Q  = (size_t)B * S * E;
    constexpr size_t N_WI = (size_t)3 * E * E;
    constexpr size_t N_BI = 3 * E;
    constexpr size_t N_WO = (size_t)E * E;

    const float* query_f = (const float*)d_in[0];
    const float* w_in_f  = (const float*)d_in[1];
    const float* b_in_f  = (const float*)d_in[2];
    const float* w_out_f = (const float*)d_in[3];
    const float* b_out_f = (const float*)d_in[4];
    float* out = (float*)d_out;

    bf16* q_buf = (bf16*)d_ws;
    bf16* k_buf = q_buf + N_Q;
    bf16* vT    = k_buf + N_Q;
    bf16* ctx   = vT + N_Q;
    bf16* query = ctx + N_Q;
    bf16* w_in  = query + N_Q;
    bf16* b_in  = w_in + N_WI;
    bf16* w_out = b_in + N_BI;
    bf16* b_out = w_out + N_WO;

    conv_all<<<2048, 256, 0, stream>>>(query_f, w_in_f, b_in_f, w_out_f, b_out_f,
                                       query, w_in, b_in, w_out, b_out);

    gemm_qk<<<dim3((M / 128) * 16), 256, 0, stream>>>(
        query, w_in, b_in, q_buf, k_buf);

    gemm_v<<<dim3((M / 128) * 8), 256, 0, stream>>>(
        query, w_in + (size_t)2048 * E, b_in, vT);

    attn10<<<dim3(512), 512, 0, stream>>>(q_buf, k_buf, vT, ctx);

    gemm_out<<<dim3((M / 128) * 8), 256, 0, stream>>>(
        ctx, w_out, b_out, out);
}

// Round 18
// 159.256 us; speedup vs baseline: 1.0627x; 1.0627x over previous
//
#include <hip/hip_runtime.h>

// Inputs: float32. Output: float32. Compute: bf16 MFMA, f32 accumulate.
typedef __bf16 bf16;
typedef __bf16 bf16x4 __attribute__((ext_vector_type(4)));
typedef __bf16 bf16x8 __attribute__((ext_vector_type(8)));
typedef float  f32x4  __attribute__((ext_vector_type(4)));
typedef short  short4v __attribute__((ext_vector_type(4)));

#define GLOAD_LDS16(g, l) __builtin_amdgcn_global_load_lds( \
    (const __attribute__((address_space(1))) void*)(g),     \
    (__attribute__((address_space(3))) void*)(l), 16, 0, 0)

// v_exp_f32 (2^x) — avoid __exp2f (collides with glibc reserved identifier)
__device__ __forceinline__ float exp2_hw(float x) { return __builtin_amdgcn_exp2f(x); }

// 16x16x16 bf16 MFMA (A/B = 4 bf16 = 2 VGPR, C/D = 4 f32) — name varies by ROCm
#if __has_builtin(__builtin_amdgcn_mfma_f32_16x16x16bf16_1k)
__device__ __forceinline__ f32x4 mfma16(bf16x4 a, bf16x4 b, f32x4 c) {
    return __builtin_amdgcn_mfma_f32_16x16x16bf16_1k(
        __builtin_bit_cast(short4v, a), __builtin_bit_cast(short4v, b), c, 0, 0, 0);
}
#elif __has_builtin(__builtin_amdgcn_mfma_f32_16x16x16_bf16)
__device__ __forceinline__ f32x4 mfma16(bf16x4 a, bf16x4 b, f32x4 c) {
    return __builtin_amdgcn_mfma_f32_16x16x16_bf16(a, b, c, 0, 0, 0);
}
#else
__device__ __forceinline__ f32x4 mfma16(bf16x4 a, bf16x4 b, f32x4 c) {
    asm volatile("v_mfma_f32_16x16x16_bf16 %0, %1, %2, %0"
                 : "+v"(c) : "v"(a), "v"(b));
    return c;
}
#endif

// ---------------------------------------------------------------------------
// all five f32 inputs -> bf16 in ONE launch (segmented grid-stride, float4)
// ---------------------------------------------------------------------------
__global__ __launch_bounds__(256) void conv_all(
    const float* __restrict__ q_f, const float* __restrict__ wi_f,
    const float* __restrict__ bi_f, const float* __restrict__ wo_f,
    const float* __restrict__ bo_f,
    bf16* __restrict__ q_o, bf16* __restrict__ wi_o, bf16* __restrict__ bi_o,
    bf16* __restrict__ wo_o, bf16* __restrict__ bo_o)
{
    constexpr int N0 = 2097152;            // query /4
    constexpr int N1 = N0 + 786432;        // + w_in /4
    constexpr int N2 = N1 + 768;           // + b_in /4
    constexpr int N3 = N2 + 262144;        // + w_out /4
    constexpr int N4 = N3 + 256;           // + b_out /4
    int i = blockIdx.x * blockDim.x + threadIdx.x;
    const int stride = gridDim.x * blockDim.x;
    for (; i < N4; i += stride) {
        const float* src; bf16* dst; int off;
        if (i < N0)      { src = q_f;  dst = q_o;  off = i; }
        else if (i < N1) { src = wi_f; dst = wi_o; off = i - N0; }
        else if (i < N2) { src = bi_f; dst = bi_o; off = i - N1; }
        else if (i < N3) { src = wo_f; dst = wo_o; off = i - N2; }
        else             { src = bo_f; dst = bo_o; off = i - N3; }
        const float4 v = *(const float4*)(src + (size_t)off * 4);
        bf16x4 o = { (bf16)v.x, (bf16)v.y, (bf16)v.z, (bf16)v.w };
        *(bf16x4*)(dst + (size_t)off * 4) = o;
    }
}

// ---------------------------------------------------------------------------
// Shared 128x128/BK=64 NT main loop, T2-swizzled LDS (round-15 verbatim,
// single non-template version — dual instantiation inflated VGPR, r16).
// acc[m][n]: D row = s (fq*4+j), col = weight-col (fr).
// ---------------------------------------------------------------------------
__device__ __forceinline__ void gemm_mainloop_128(
    const bf16* __restrict__ A, const bf16* __restrict__ B, int K,
    int bm, int bn, bf16* As, bf16* Bs, f32x4 (&acc)[4][4])
{
    const int tid  = threadIdx.x;
    const int lane = tid & 63, fr = lane & 15, fq = lane >> 4;
    const int wave = tid >> 6;
    const int wr   = (wave >> 1) * 64, wc = (wave & 1) * 64;
    const int srow = tid >> 3, sj = tid & 7;
    const int sjs  = (sj ^ (srow & 7)) * 8;
    const int xo0  = (fq ^ (fr & 7)) * 8;
    const int xo1  = ((4 + fq) ^ (fr & 7)) * 8;

    const bf16* Ag = A + (size_t)(bm * 128 + srow) * K + sjs;
    const bf16* Bg = B + (size_t)(bn * 128 + srow) * K + sjs;
    bf16* Asw = As + srow * 64 + sj * 8;
    bf16* Bsw = Bs + srow * 64 + sj * 8;

    for (int k0 = 0; k0 < K; k0 += 64) {
        __syncthreads();
#pragma unroll
        for (int it = 0; it < 4; ++it)
            GLOAD_LDS16(Ag + k0 + (size_t)it * 32 * K, Asw + it * 32 * 64);
#pragma unroll
        for (int it = 0; it < 4; ++it)
            GLOAD_LDS16(Bg + k0 + (size_t)it * 32 * K, Bsw + it * 32 * 64);
        asm volatile("s_waitcnt vmcnt(0)" ::: "memory");
        __syncthreads();

#pragma unroll
        for (int ks = 0; ks < 2; ++ks) {
            const int xo = ks ? xo1 : xo0;
            bf16x8 a[4], b[4];
#pragma unroll
            for (int m = 0; m < 4; ++m)
                a[m] = *(const bf16x8*)&As[(wr + m * 16 + fr) * 64 + xo];
#pragma unroll
            for (int n = 0; n < 4; ++n)
                b[n] = *(const bf16x8*)&Bs[(wc + n * 16 + fr) * 64 + xo];
#pragma unroll
            for (int m = 0; m < 4; ++m)
#pragma unroll
                for (int n = 0; n < 4; ++n)
                    acc[m][n] = __builtin_amdgcn_mfma_f32_16x16x32_bf16(a[m], b[n], acc[m][n], 0, 0, 0);
        }
    }
}

// ---------------------------------------------------------------------------
// QKV projection -> head-major q[bh][s][64] (PRE-SCALED by 0.125*log2e),
// k[bh][s][64], vT[bh][64][s]. Round-15 epilogue verbatim.
// T1 XCD remap: nwg=1536 (%8==0) -> one XCD owns 8 consecutive A-panels
// (24 bn-blocks each) -> A-panel L2-resident across its 24 reuses.
// ---------------------------------------------------------------------------
__global__ __launch_bounds__(256) void gemm_qkv(
    const bf16* __restrict__ A, const bf16* __restrict__ B,
    const bf16* __restrict__ bias,
    bf16* __restrict__ qb_, bf16* __restrict__ kb_, bf16* __restrict__ vt_)
{
    constexpr int K = 1024, NTN = 24;
    constexpr float QSCALE = 0.18033688011112042f;  // 0.125 * log2(e)
    __shared__ bf16 As[128 * 64];
    __shared__ bf16 Bs[128 * 64];
    const int orig = (blockIdx.x & 7) * 192 + (blockIdx.x >> 3);  // bijective
    const int bm = orig / NTN, bn = orig % NTN;

    f32x4 acc[4][4] = {};
    gemm_mainloop_128(A, B, K, bm, bn, As, Bs, acc);

    const int tid = threadIdx.x, lane = tid & 63;
    const int fr = lane & 15, fq = lane >> 4;
    const int wave = tid >> 6;
    const int wr = (wave >> 1) * 64, wc = (wave & 1) * 64;

    const int colbase = bn * 128 + wc;
    const int part = colbase >> 10;          // 0=Q 1=K 2=V (block-uniform)

#pragma unroll
    for (int n = 0; n < 4; ++n) {
        const int col = colbase + n * 16 + fr;
        const float bv = (float)bias[col];
        const int cl = col & 1023, h = cl >> 6, d = cl & 63;
#pragma unroll
        for (int m = 0; m < 4; ++m) {
            const int row0 = bm * 128 + wr + m * 16 + fq * 4;
            const int bb = row0 >> 11, s0 = row0 & 2047;
            const int bh = bb * 16 + h;
            if (part == 0) {
#pragma unroll
                for (int j = 0; j < 4; ++j)
                    qb_[((size_t)bh * 2048 + s0 + j) * 64 + d] = (bf16)((acc[m][n][j] + bv) * QSCALE);
            } else if (part == 1) {
#pragma unroll
                for (int j = 0; j < 4; ++j)
                    kb_[((size_t)bh * 2048 + s0 + j) * 64 + d] = (bf16)(acc[m][n][j] + bv);
            } else {
                bf16x4 o;
#pragma unroll
                for (int j = 0; j < 4; ++j) o[j] = (bf16)(acc[m][n][j] + bv);
                *(bf16x4*)&vt_[((size_t)bh * 64 + d) * 2048 + s0] = o;
            }
        }
    }
}

// ---------------------------------------------------------------------------
// Output projection (f32 out), round-15 verbatim + T1 remap (nwg=512, %8==0).
// ---------------------------------------------------------------------------
__global__ __launch_bounds__(256) void gemm_out(
    const bf16* __restrict__ A, const bf16* __restrict__ B,
    const bf16* __restrict__ bias, float* __restrict__ C)
{
    constexpr int K = 1024, N = 1024, NTN = 8;
    __shared__ bf16 As[128 * 64];
    __shared__ bf16 Bs[128 * 64];
    const int orig = (blockIdx.x & 7) * 64 + (blockIdx.x >> 3);   // bijective
    const int bm = orig / NTN, bn = orig % NTN;

    f32x4 acc[4][4] = {};
    gemm_mainloop_128(A, B, K, bm, bn, As, Bs, acc);

    const int tid = threadIdx.x, lane = tid & 63;
    const int fr = lane & 15, fq = lane >> 4;
    const int wave = tid >> 6;
    const int wr = (wave >> 1) * 64, wc = (wave & 1) * 64;

#pragma unroll
    for (int n = 0; n < 4; ++n) {
        const int col = bn * 128 + wc + n * 16 + fr;
        const float bv = (float)bias[col];
#pragma unroll
        for (int m = 0; m < 4; ++m) {
            const int row0 = bm * 128 + wr + m * 16 + fq * 4;
#pragma unroll
            for (int j = 0; j < 4; ++j)
                C[(size_t)(row0 + j) * N + col] = acc[m][n][j] + bv;
        }
    }
}

// ---------------------------------------------------------------------------
// Causal flash attention v10 (round-15 verbatim): causal pairing, 8 waves x
// 16 q, swapped QK^T, register-direct PV, ones-column denominator, nmax
// guard, no max tracking, 128-key barrier rounds (2x64 sub-tiles).
// ---------------------------------------------------------------------------
__global__ __launch_bounds__(512, 4) void attn10(
    const bf16* __restrict__ qb_, const bf16* __restrict__ kb_,
    const bf16* __restrict__ vt_, bf16* __restrict__ ctx)
{
    constexpr int S = 2048, EO = 1024;
    constexpr float NEG = -3.0e38f;
    __shared__ bf16 Ks[2][2][64 * 64];   // [dbuf][64-key sub-tile]
    __shared__ bf16 Vs[2][2][64 * 64];

    // bijective remap: 8 heads per XCD (64 blocks/XCD)
    const int idx = blockIdx.x;                 // 0..511
    const int orig = (idx & 7) * 64 + (idx >> 3);
    const int bh = orig >> 3;                   // 0..63
    const int p  = orig & 7;                    // pair index 0..7
    const int bb = bh >> 4, h = bh & 15;

    const int tid = threadIdx.x, lane = tid & 63, wave = tid >> 6;  // wave 0..7
    const int fr = lane & 15, fq = lane >> 4;

    const bf16* kh = kb_ + (size_t)bh * S * 64;
    const bf16* vh = vt_ + (size_t)bh * 64 * S;
    const bf16* qh = qb_ + (size_t)bh * S * 64;

    const int xo0 = (fq ^ (fr & 7)) * 8;
    const int xo1 = ((4 + fq) ^ (fr & 7)) * 8;

    // hoisted per-thread constants for QK/PV LDS addressing
    int krb[4], vslot[4], vrow[4];
#pragma unroll
    for (int n = 0; n < 4; ++n) {
        krb[n]   = (n * 16 + fr) * 64;
        vslot[n] = ((n * 2 + (fq >> 1)) ^ (fr & 7)) * 8 + (fq & 1) * 4;
        vrow[n]  = (n * 16 + fr) * 64;
    }

    // staging: 512 threads x 16B per sub-tile per operand (4 loads/round)
    const int r0 = tid >> 3, j0 = tid & 7;      // r0 0..63
    const int js = (j0 ^ (r0 & 7)) * 8;

#define STAGE128(buf, kt2)                                                    \
    do {                                                                      \
        GLOAD_LDS16(kh + (size_t)(((kt2) * 2) * 64 + r0) * 64 + js,           \
                    &Ks[buf][0][(r0 * 8 + j0) * 8]);                          \
        GLOAD_LDS16(kh + (size_t)(((kt2) * 2 + 1) * 64 + r0) * 64 + js,       \
                    &Ks[buf][1][(r0 * 8 + j0) * 8]);                          \
        GLOAD_LDS16(vh + (size_t)r0 * S + ((kt2) * 2) * 64 + js,              \
                    &Vs[buf][0][(r0 * 8 + j0) * 8]);                          \
        GLOAD_LDS16(vh + (size_t)r0 * S + ((kt2) * 2 + 1) * 64 + js,          \
                    &Vs[buf][1][(r0 * 8 + j0) * 8]);                          \
    } while (0)

    const bf16 one = (bf16)1.0f;
    const bf16x4 ones = { one, one, one, one };

#pragma unroll
    for (int sub = 0; sub < 2; ++sub) {
        const int qb = sub ? p : (15 - p);      // heavy q-block first
        const int q0 = qb * 128 + wave * 16;    // wave's first q row

        // Q fragments: B-operand of swapped QK^T; lane holds q = q0 + fr
        bf16x8 qf0, qf1;
        {
            const bf16* qr = qh + (size_t)(q0 + fr) * 64;
            qf0 = *(const bf16x8*)(qr + fq * 8);
            qf1 = *(const bf16x8*)(qr + 32 + fq * 8);
        }

        f32x4 acc[4] = {};   // O: acc[n2][j] -> d = n2*16+fr, q = q0 + fq*4+j
        f32x4 acc1 = {};     // softmax denominator, same row layout

        // protect LDS from previous sub's readers, then stage round 0
        __syncthreads();
        STAGE128(0, 0);
        asm volatile("s_waitcnt vmcnt(0)" ::: "memory");
        __syncthreads();

        int cur = 0;
        for (int kt2 = 0; kt2 <= qb; ++kt2) {   // 128-key rounds
            if (kt2 < qb) STAGE128(cur ^ 1, kt2 + 1);

#pragma unroll
            for (int half = 0; half < 2; ++half) {
                const int kt = 2 * kt2 + half;  // 64-key tile index
                // highest n-block with any unmasked key (<0: wave done)
                const int nmax = (q0 + 15 - kt * 64) >> 4;
                if (nmax < 0) continue;

                // S^T[key][q] = K . Q^T  (A = K frag, B = Q frag)
                f32x4 s[4];
                __builtin_amdgcn_s_setprio(1);
#pragma unroll
                for (int n = 0; n < 4; ++n) {
                    if (n > nmax) continue;
                    s[n] = f32x4{};
                    bf16x8 k0v = *(const bf16x8*)&Ks[cur][half][krb[n] + xo0];
                    bf16x8 k1v = *(const bf16x8*)&Ks[cur][half][krb[n] + xo1];
                    s[n] = __builtin_amdgcn_mfma_f32_16x16x32_bf16(k0v, qf0, s[n], 0, 0, 0);
                    s[n] = __builtin_amdgcn_mfma_f32_16x16x32_bf16(k1v, qf1, s[n], 0, 0, 0);
                }
                __builtin_amdgcn_s_setprio(0);

                // causal mask only on the wave's boundary tile (nmax <= 3)
                if (nmax <= 3) {
                    const int qrel = q0 - kt * 64 + fr;
#pragma unroll
                    for (int n = 0; n < 4; ++n) {
                        if (n > nmax) continue;
#pragma unroll
                        for (int j = 0; j < 4; ++j)
                            if (n * 16 + fq * 4 + j > qrel) s[n][j] = NEG;
                    }
                }

                // P = exp2(s); denominator via ones-column MFMA
                bf16x4 pb[4];
#pragma unroll
                for (int n = 0; n < 4; ++n) {
                    if (n > nmax) continue;
                    pb[n][0] = (bf16)exp2_hw(s[n][0]);
                    pb[n][1] = (bf16)exp2_hw(s[n][1]);
                    pb[n][2] = (bf16)exp2_hw(s[n][2]);
                    pb[n][3] = (bf16)exp2_hw(s[n][3]);
                    acc1 = mfma16(pb[n], ones, acc1);
                }

                // PV: O[q][d] += P.V via mfma 16x16x16 (A = pb from registers)
                __builtin_amdgcn_s_setprio(1);
#pragma unroll
                for (int n = 0; n < 4; ++n) {          // key block
                    if (n > nmax) continue;
#pragma unroll
                    for (int n2 = 0; n2 < 4; ++n2) {   // d block
                        bf16x4 vf = *(const bf16x4*)&Vs[cur][half][vrow[n2] + vslot[n]];
                        acc[n2] = mfma16(pb[n], vf, acc[n2]);
                    }
                }
                __builtin_amdgcn_s_setprio(0);
            }

            asm volatile("s_waitcnt vmcnt(0)" ::: "memory");
            __syncthreads();
            cur ^= 1;
        }

        // normalize: acc1[j] is the full denominator for q = q0 + fq*4 + j
        float linv[4];
#pragma unroll
        for (int j = 0; j < 4; ++j) linv[j] = __builtin_amdgcn_rcpf(acc1[j]);

#pragma unroll
        for (int n2 = 0; n2 < 4; ++n2)
#pragma unroll
            for (int j = 0; j < 4; ++j) {
                int qr_ = q0 + fq * 4 + j;
                ctx[((size_t)bb * S + qr_) * EO + h * 64 + n2 * 16 + fr] =
                    (bf16)(acc[n2][j] * linv[j]);
            }
    }
#undef STAGE128
}

// ---------------------------------------------------------------------------
extern "C" void kernel_launch(void* const* d_in, const int* in_sizes, int n_in,
                              void* d_out, int out_size, void* d_ws, size_t ws_size,
                              hipStream_t stream)
{
    constexpr int B = 4, S = 2048, E = 1024;
    constexpr int M = B * S;
    constexpr size_t N_Q  = (size_t)B * S * E;
    constexpr size_t N_WI = (size_t)3 * E * E;
    constexpr size_t N_BI = 3 * E;
    constexpr size_t N_WO = (size_t)E * E;

    const float* query_f = (const float*)d_in[0];
    const float* w_in_f  = (const float*)d_in[1];
    const float* b_in_f  = (const float*)d_in[2];
    const float* w_out_f = (const float*)d_in[3];
    const float* b_out_f = (const float*)d_in[4];
    float* out = (float*)d_out;

    bf16* q_buf = (bf16*)d_ws;
    bf16* k_buf = q_buf + N_Q;
    bf16* vT    = k_buf + N_Q;
    bf16* ctx   = vT + N_Q;
    bf16* query = ctx + N_Q;
    bf16* w_in  = query + N_Q;
    bf16* b_in  = w_in + N_WI;
    bf16* w_out = b_in + N_BI;
    bf16* b_out = w_out + N_WO;

    conv_all<<<2048, 256, 0, stream>>>(query_f, w_in_f, b_in_f, w_out_f, b_out_f,
                                       query, w_in, b_in, w_out, b_out);

    gemm_qkv<<<dim3((M / 128) * (3 * E / 128)), 256, 0, stream>>>(
        query, w_in, b_in, q_buf, k_buf, vT);

    attn10<<<dim3(512), 512, 0, stream>>>(q_buf, k_buf, vT, ctx);

    gemm_out<<<dim3((M / 128) * 8), 256, 0, stream>>>(
        ctx, w_out, b_out, out);
}